// Round 3
// baseline (317.540 us; speedup 1.0000x reference)
//
#include <hip/hip_runtime.h>
#include <math.h>

#define BS 8
#define NPTS 16384
#define C 32
#define K 256
#define KNNK 16
#define NBINS 512
#define BINW 0.00025f
#define CAP 4096

// ---------------------------------------------------------------------------
// Phase 1: fused regression-logit GEMM + exp + weighted position accumulation.
// Thread = keypoint-pair (t, t+128); block = one disjoint point-chunk.
// W columns live in registers; per-point features are wave-uniform loads
// (compiler emits s_load -> SGPR operands, HW broadcast). Pooling-head bias is
// constant over n and cancels in the segment softmax, so W_pool is unused.
// Logits bounded (|L|<~4) so exp() without max-subtraction is safe and fp32
// partials merge across blocks. nsplit=512 -> 8192 waves (32/CU) hides the
// ~300cyc scalar-load latency that capped round 2 at VALUBusy=33%.
// ---------------------------------------------------------------------------
__global__ __launch_bounds__(128, 8) void k_logits(
    const float* __restrict__ f, const float* __restrict__ pos,
    const float* __restrict__ Wr, float* __restrict__ partials, int nsplit) {
  int b = blockIdx.x / nsplit;
  int split = blockIdx.x % nsplit;
  int chunk = NPTS / nsplit;
  int t = threadIdx.x;   // 0..127; handles keypoints t and t+128

  float w0[C], w1[C];
#pragma unroll
  for (int c = 0; c < C; c++) {
    w0[c] = Wr[c * K + t];
    w1[c] = Wr[c * K + t + 128];
  }

  float l0s = 0.f, x0s = 0.f, y0s = 0.f, z0s = 0.f;
  float l1s = 0.f, x1s = 0.f, y1s = 0.f, z1s = 0.f;

  int pbase = b * NPTS + split * chunk;
  const float4* fb = (const float4*)(f + (size_t)pbase * C);
  const float* pb = pos + (size_t)pbase * 3;

#pragma unroll 2
  for (int p = 0; p < chunk; p++) {
    float4 fv[8];
#pragma unroll
    for (int q = 0; q < 8; q++) fv[q] = fb[(size_t)p * 8 + q];
    float l0 = 0.f, l1 = 0.f;
#pragma unroll
    for (int q = 0; q < 8; q++) {
      l0 += fv[q].x * w0[4*q] + fv[q].y * w0[4*q+1] + fv[q].z * w0[4*q+2] + fv[q].w * w0[4*q+3];
      l1 += fv[q].x * w1[4*q] + fv[q].y * w1[4*q+1] + fv[q].z * w1[4*q+2] + fv[q].w * w1[4*q+3];
    }
    float e0 = __expf(l0), e1 = __expf(l1);
    float px = pb[p*3+0], py = pb[p*3+1], pz = pb[p*3+2];
    l0s += e0; x0s += e0 * px; y0s += e0 * py; z0s += e0 * pz;
    l1s += e1; x1s += e1 * px; y1s += e1 * py; z1s += e1 * pz;
  }

  float4* po = (float4*)partials;
  po[(size_t)blockIdx.x * 256 + t]       = make_float4(l0s, x0s, y0s, z0s);
  po[(size_t)blockIdx.x * 256 + t + 128] = make_float4(l1s, x1s, y1s, z1s);
}

// ---------------------------------------------------------------------------
// Phase 1b: merge partials -> keypoints. 64 blocks (8/graph x 32 kp), each
// thread sums nsplit/8 float4s coalesced (32 consecutive kp per s-plane),
// then an 8-way LDS tree. fp32 segmented sums: relerr ~4e-6, negligible vs
// the 2e-2 threshold (round-2 fp64 merge gave absmax 2.4e-4 from fp32 output
// rounding elsewhere).
// ---------------------------------------------------------------------------
__global__ __launch_bounds__(256) void k_merge(
    const float* __restrict__ partials, float* __restrict__ keypoints,
    int nsplit) {
  int g = blockIdx.x;
  int b = g >> 3, kg = g & 7;
  int t = threadIdx.x;
  int kl = t & 31;            // kp within group
  int kp = kg * 32 + kl;
  int seg = t >> 5;           // 0..7
  int cnt = nsplit / 8;
  const float4* po = (const float4*)partials;
  float sl = 0.f, sx = 0.f, sy = 0.f, sz = 0.f;
  for (int j = 0; j < cnt; j++) {
    float4 v = po[((size_t)b * nsplit + seg * cnt + j) * 256 + kp];
    sl += v.x; sx += v.y; sy += v.z; sz += v.w;
  }
  __shared__ float sd[8][32][4];
  sd[seg][kl][0] = sl; sd[seg][kl][1] = sx;
  sd[seg][kl][2] = sy; sd[seg][kl][3] = sz;
  __syncthreads();
  if (seg == 0) {
    float L = 0.f, X = 0.f, Y = 0.f, Z = 0.f;
#pragma unroll
    for (int i = 0; i < 8; i++) {
      L += sd[i][kl][0]; X += sd[i][kl][1];
      Y += sd[i][kl][2]; Z += sd[i][kl][3];
    }
    float inv = 1.f / L;
    keypoints[(b * K + kp) * 3 + 0] = X * inv;
    keypoints[(b * K + kp) * 3 + 1] = Y * inv;
    keypoints[(b * K + kp) * 3 + 2] = Z * inv;
  }
}

// ---------------------------------------------------------------------------
// Phase 2 (fused, one block per graph, 1024 threads):
//   A. keypoint centroid + max keypoint-centroid distance (shuffle reduce)
//   B. histogram of d2(point, centroid) -- catch-all bin SKIPPED so only the
//      ~200 in-range points hit LDS atomics (no serialization pile-up)
//   C. radius: T >= d16(centroid); R = T + 2*maxdiam (triangle-ineq exact);
//      if <16 points in histogram range -> R = inf -> fallback (correct)
//   D. compact candidates (~40/graph) into LDS
//   E. exact top-16 per keypoint over LDS candidates (global-scan fallback
//      if candidate cap exceeded -- slow but correct, never triggers here)
// ---------------------------------------------------------------------------
__global__ __launch_bounds__(1024) void k_graph(
    const float* __restrict__ pos, const float* __restrict__ keypoints,
    int* __restrict__ knn) {
  int b = blockIdx.x;
  int t = threadIdx.x;
  int lane = t & 63, wave = t >> 6;

  __shared__ float kxs[256], kys[256], kzs[256];
  __shared__ float wred[16][3];
  __shared__ float bc[6];          // cx, cy, cz, maxdiam, Rf2
  __shared__ unsigned hist[NBINS];
  __shared__ unsigned lcnt, ovf;
  __shared__ float cxs[CAP], cys[CAP], czs[CAP];
  __shared__ int cis[CAP];

  if (t < 256) {
    kxs[t] = keypoints[(b * K + t) * 3 + 0];
    kys[t] = keypoints[(b * K + t) * 3 + 1];
    kzs[t] = keypoints[(b * K + t) * 3 + 2];
  }
  for (int i = t; i < NBINS; i += 1024) hist[i] = 0;
  if (t == 0) { lcnt = 0; ovf = 0; }
  __syncthreads();

  // --- A: centroid ---
  float sx = 0.f, sy = 0.f, sz = 0.f;
  if (t < 256) { sx = kxs[t]; sy = kys[t]; sz = kzs[t]; }
#pragma unroll
  for (int off = 32; off; off >>= 1) {
    sx += __shfl_xor(sx, off, 64);
    sy += __shfl_xor(sy, off, 64);
    sz += __shfl_xor(sz, off, 64);
  }
  if (lane == 0) { wred[wave][0] = sx; wred[wave][1] = sy; wred[wave][2] = sz; }
  __syncthreads();
  if (t == 0) {
    float X = 0.f, Y = 0.f, Z = 0.f;
#pragma unroll
    for (int i = 0; i < 16; i++) { X += wred[i][0]; Y += wred[i][1]; Z += wred[i][2]; }
    bc[0] = X / K; bc[1] = Y / K; bc[2] = Z / K;
  }
  __syncthreads();
  float cx = bc[0], cy = bc[1], cz = bc[2];
  // --- A2: max keypoint distance from centroid ---
  float md = 0.f;
  if (t < 256) {
    float dx = kxs[t] - cx, dy = kys[t] - cy, dz = kzs[t] - cz;
    md = dx * dx + dy * dy + dz * dz;
  }
#pragma unroll
  for (int off = 32; off; off >>= 1) md = fmaxf(md, __shfl_xor(md, off, 64));
  if (lane == 0) wred[wave][0] = md;
  __syncthreads();
  if (t == 0) {
    float m = 0.f;
#pragma unroll
    for (int i = 0; i < 16; i++) m = fmaxf(m, wred[i][0]);
    bc[3] = sqrtf(m);
  }
  __syncthreads();

  // --- B: histogram (in-range bins only) ---
#pragma unroll 1
  for (int i = 0; i < 16; i++) {
    int p = b * NPTS + i * 1024 + t;
    float dx = pos[p * 3 + 0] - cx, dy = pos[p * 3 + 1] - cy, dz = pos[p * 3 + 2] - cz;
    float d2 = dx * dx + dy * dy + dz * dz;
    int bin = (int)(d2 * (1.0f / BINW));
    if (bin < NBINS - 1) atomicAdd(&hist[bin], 1u);
  }
  __syncthreads();

  // --- C: select radius ---
  if (t == 0) {
    unsigned cum = 0; float T2 = -1.f;
    for (int i = 0; i < NBINS - 1; i++) {
      cum += hist[i];
      if (cum >= KNNK) { T2 = (i + 1) * BINW; break; }
    }
    if (T2 < 0.f) bc[4] = 3.0e38f;           // degenerate: keep everything
    else {
      float Rf = sqrtf(T2) + 2.f * bc[3];
      bc[4] = Rf * Rf;
    }
  }
  __syncthreads();
  float r2 = bc[4];

  // --- D: compact candidates into LDS ---
#pragma unroll 1
  for (int i = 0; i < 16; i++) {
    int pl = i * 1024 + t;
    int p = b * NPTS + pl;
    float px = pos[p * 3 + 0], py = pos[p * 3 + 1], pz = pos[p * 3 + 2];
    float dx = px - cx, dy = py - cy, dz = pz - cz;
    float d2 = dx * dx + dy * dy + dz * dz;
    if (d2 <= r2) {
      unsigned u = atomicAdd(&lcnt, 1u);
      if (u < CAP) { cxs[u] = px; cys[u] = py; czs[u] = pz; cis[u] = pl; }
      else ovf = 1;
    }
  }
  __syncthreads();

  // --- E: exact top-16 per keypoint ---
  if (t < 256) {
    float kx = kxs[t], ky = kys[t], kz = kzs[t];
    float dd[KNNK]; int ii[KNNK];
#pragma unroll
    for (int j = 0; j < KNNK; j++) { dd[j] = 1e30f; ii[j] = 0; }
    float mx = 1e30f;
    if (!ovf) {
      int n = (int)lcnt;
      for (int j = 0; j < n; j++) {
        float dx = kx - cxs[j], dy = ky - cys[j], dz = kz - czs[j];
        float d2 = dx * dx + dy * dy + dz * dz;
        if (d2 < mx) {
          int sm = 0; float bv = dd[0];
#pragma unroll
          for (int s = 1; s < KNNK; s++) if (dd[s] > bv) { bv = dd[s]; sm = s; }
#pragma unroll
          for (int s = 0; s < KNNK; s++) if (s == sm) { dd[s] = d2; ii[s] = t == t ? cis[j] : 0; }
          mx = dd[0];
#pragma unroll
          for (int s = 1; s < KNNK; s++) mx = fmaxf(mx, dd[s]);
        }
      }
    } else {
      // correctness fallback: scan all points (never triggers on sane data)
      for (int j = 0; j < NPTS; j++) {
        const float* pp = pos + (size_t)(b * NPTS + j) * 3;
        float dx = kx - pp[0], dy = ky - pp[1], dz = kz - pp[2];
        float d2 = dx * dx + dy * dy + dz * dz;
        if (d2 < mx) {
          int sm = 0; float bv = dd[0];
#pragma unroll
          for (int s = 1; s < KNNK; s++) if (dd[s] > bv) { bv = dd[s]; sm = s; }
#pragma unroll
          for (int s = 0; s < KNNK; s++) if (s == sm) { dd[s] = d2; ii[s] = j; }
          mx = dd[0];
#pragma unroll
          for (int s = 1; s < KNNK; s++) mx = fmaxf(mx, dd[s]);
        }
      }
    }
    for (int j = 0; j < KNNK; j++) knn[((size_t)(b * K + t)) * KNNK + j] = ii[j];
  }
}

// ---------------------------------------------------------------------------
// Phase 3: gather 16 neighbor feature rows, mean, 32x32 linear.
// ---------------------------------------------------------------------------
__global__ __launch_bounds__(256) void k_extract(
    const float* __restrict__ f, const int* __restrict__ knn,
    const float* __restrict__ We, float* __restrict__ out) {
  __shared__ float P[8][C + 1];
  int tid = threadIdx.x;
  int kp = tid >> 5, c = tid & 31;
  int gk = blockIdx.x * 8 + kp;   // 0..2047
  int b = gk >> 8;
  float s = 0.f;
#pragma unroll
  for (int j = 0; j < KNNK; j++) {
    int pl = knn[(size_t)gk * KNNK + j];
    s += f[((size_t)(b * NPTS + pl)) * C + c];
  }
  P[kp][c] = s * (1.f / KNNK);
  __syncthreads();
  float r = 0.f;
#pragma unroll
  for (int cc = 0; cc < C; cc++) r += P[kp][cc] * We[cc * C + c];
  out[(size_t)gk * C + c] = r;
}

extern "C" void kernel_launch(void* const* d_in, const int* in_sizes, int n_in,
                              void* d_out, int out_size, void* d_ws, size_t ws_size,
                              hipStream_t stream) {
  const float* f   = (const float*)d_in[0];
  const float* pos = (const float*)d_in[1];
  // d_in[2] = W_pool: mathematically unused (bias cancels in segment softmax)
  const float* Wr  = (const float*)d_in[3];
  const float* We  = (const float*)d_in[4];
  float* out = (float*)d_out;

  // nsplit high -> more waves to hide scalar-load latency in k_logits.
  // partials = BS * nsplit * 256 * 16 B.
  size_t fixed = 24576 + 131072 + 4096;    // keypoints + knn + pad
  int nsplit;
  if (ws_size >= (size_t)BS * 512 * 256 * 16 + fixed) nsplit = 512;
  else if (ws_size >= (size_t)BS * 128 * 256 * 16 + fixed) nsplit = 128;
  else nsplit = 32;
  size_t partials_bytes = (size_t)BS * nsplit * 256 * 16;

  char* ws = (char*)d_ws;
  float* partials  = (float*)(ws + 0);
  float* keypoints = (float*)(ws + partials_bytes);          // [8][256][3] f32
  int*   knn       = (int*)(ws + partials_bytes + 24576);    // [8][256][16] i32

  k_logits <<<dim3(BS * nsplit), dim3(128),  0, stream>>>(f, pos, Wr, partials, nsplit);
  k_merge  <<<dim3(64),          dim3(256),  0, stream>>>(partials, keypoints, nsplit);
  k_graph  <<<dim3(BS),          dim3(1024), 0, stream>>>(pos, keypoints, knn);
  k_extract<<<dim3((BS * K) / 8), dim3(256), 0, stream>>>(f, knn, We, out);
}

// Round 4
// 169.898 us; speedup vs baseline: 1.8690x; 1.8690x over previous
//
#include <hip/hip_runtime.h>
#include <math.h>

#define BS 8
#define NPTS 16384
#define C 32
#define K 256
#define KNNK 16
#define NBINS 512
#define BINW 0.00025f
#define CAP 4096

// ---------------------------------------------------------------------------
// Phase 1: fused regression-logit GEMM + exp + weighted position accumulation.
// Thread = keypoint-pair (t, t+128); block = one disjoint point-chunk.
// W columns nominally in registers; per-point features are wave-uniform loads
// (HW broadcast). Pooling-head bias is constant over n and cancels in the
// segment softmax, so W_pool is unused. Logits bounded (|L|<~4) so exp()
// without max-subtraction is safe; fp32 partials merge across blocks.
// launch_bounds(128,2): natural allocation is ~52 VGPR (round-2 measured) --
// forcing 8 waves/EU caused catastrophic spills (round-3: VGPR 32, 145 MB
// scratch writes). 52 VGPR already allows 8 waves/SIMD; occupancy comes from
// grid size: nsplit=512 -> 4096 blocks x 2 waves = 8192 waves.
// ---------------------------------------------------------------------------
__global__ __launch_bounds__(128, 2) void k_logits(
    const float* __restrict__ f, const float* __restrict__ pos,
    const float* __restrict__ Wr, float* __restrict__ partials, int nsplit) {
  int b = blockIdx.x / nsplit;
  int split = blockIdx.x % nsplit;
  int chunk = NPTS / nsplit;
  int t = threadIdx.x;   // 0..127; handles keypoints t and t+128

  float w0[C], w1[C];
#pragma unroll
  for (int c = 0; c < C; c++) {
    w0[c] = Wr[c * K + t];
    w1[c] = Wr[c * K + t + 128];
  }

  float l0s = 0.f, x0s = 0.f, y0s = 0.f, z0s = 0.f;
  float l1s = 0.f, x1s = 0.f, y1s = 0.f, z1s = 0.f;

  int pbase = b * NPTS + split * chunk;
  const float4* fb = (const float4*)(f + (size_t)pbase * C);
  const float* pb = pos + (size_t)pbase * 3;

#pragma unroll 2
  for (int p = 0; p < chunk; p++) {
    float4 fv[8];
#pragma unroll
    for (int q = 0; q < 8; q++) fv[q] = fb[(size_t)p * 8 + q];
    float l0 = 0.f, l1 = 0.f;
#pragma unroll
    for (int q = 0; q < 8; q++) {
      l0 += fv[q].x * w0[4*q] + fv[q].y * w0[4*q+1] + fv[q].z * w0[4*q+2] + fv[q].w * w0[4*q+3];
      l1 += fv[q].x * w1[4*q] + fv[q].y * w1[4*q+1] + fv[q].z * w1[4*q+2] + fv[q].w * w1[4*q+3];
    }
    float e0 = __expf(l0), e1 = __expf(l1);
    float px = pb[p*3+0], py = pb[p*3+1], pz = pb[p*3+2];
    l0s += e0; x0s += e0 * px; y0s += e0 * py; z0s += e0 * pz;
    l1s += e1; x1s += e1 * px; y1s += e1 * py; z1s += e1 * pz;
  }

  float4* po = (float4*)partials;
  po[(size_t)blockIdx.x * 256 + t]       = make_float4(l0s, x0s, y0s, z0s);
  po[(size_t)blockIdx.x * 256 + t + 128] = make_float4(l1s, x1s, y1s, z1s);
}

// ---------------------------------------------------------------------------
// Phase 1b: merge partials -> keypoints. 128 blocks (16 kp-groups x 8 graphs);
// each thread sums nsplit/16 float4s; 16 consecutive kp per lane-group keeps
// reads in 256B contiguous segments. fp32 segmented sums: relerr ~4e-6,
// negligible vs the 2e-2 output threshold (round-2/3 absmax 2.4e-4).
// ---------------------------------------------------------------------------
__global__ __launch_bounds__(256) void k_merge(
    const float* __restrict__ partials, float* __restrict__ keypoints,
    int nsplit) {
  int g = blockIdx.x;          // 0..127
  int b = g >> 4, kg = g & 15; // 16 kp-groups of 16 kp
  int t = threadIdx.x;
  int kl = t & 15;
  int kp = kg * 16 + kl;
  int seg = t >> 4;            // 0..15
  int cnt = nsplit / 16;
  const float4* po = (const float4*)partials;
  float sl = 0.f, sx = 0.f, sy = 0.f, sz = 0.f;
  for (int j = 0; j < cnt; j++) {
    float4 v = po[((size_t)b * nsplit + seg * cnt + j) * 256 + kp];
    sl += v.x; sx += v.y; sy += v.z; sz += v.w;
  }
  __shared__ float sd[16][16][4];
  sd[seg][kl][0] = sl; sd[seg][kl][1] = sx;
  sd[seg][kl][2] = sy; sd[seg][kl][3] = sz;
  __syncthreads();
  if (seg == 0) {
    float L = 0.f, X = 0.f, Y = 0.f, Z = 0.f;
#pragma unroll
    for (int i = 0; i < 16; i++) {
      L += sd[i][kl][0]; X += sd[i][kl][1];
      Y += sd[i][kl][2]; Z += sd[i][kl][3];
    }
    float inv = 1.f / L;
    keypoints[(b * K + kp) * 3 + 0] = X * inv;
    keypoints[(b * K + kp) * 3 + 1] = Y * inv;
    keypoints[(b * K + kp) * 3 + 2] = Z * inv;
  }
}

// ---------------------------------------------------------------------------
// Phase 2 (fused, one block per graph, 1024 threads):
//   A. keypoint centroid + max keypoint-centroid distance (shuffle reduce)
//   B. histogram of d2(point, centroid) -- catch-all bin SKIPPED so only the
//      ~200 in-range points hit LDS atomics (no serialization pile-up)
//   C. radius: T >= d16(centroid); R = T + 2*maxdiam (triangle-ineq exact);
//      if <16 points in histogram range -> R = inf -> fallback (correct)
//   D. compact candidates (~40/graph) into LDS
//   E. exact top-16 per keypoint over LDS candidates (global-scan fallback
//      if candidate cap exceeded -- slow but correct, never triggers here)
// ---------------------------------------------------------------------------
__global__ __launch_bounds__(1024) void k_graph(
    const float* __restrict__ pos, const float* __restrict__ keypoints,
    int* __restrict__ knn) {
  int b = blockIdx.x;
  int t = threadIdx.x;
  int lane = t & 63, wave = t >> 6;

  __shared__ float kxs[256], kys[256], kzs[256];
  __shared__ float wred[16][3];
  __shared__ float bc[6];          // cx, cy, cz, maxdiam, Rf2
  __shared__ unsigned hist[NBINS];
  __shared__ unsigned lcnt, ovf;
  __shared__ float cxs[CAP], cys[CAP], czs[CAP];
  __shared__ int cis[CAP];

  if (t < 256) {
    kxs[t] = keypoints[(b * K + t) * 3 + 0];
    kys[t] = keypoints[(b * K + t) * 3 + 1];
    kzs[t] = keypoints[(b * K + t) * 3 + 2];
  }
  for (int i = t; i < NBINS; i += 1024) hist[i] = 0;
  if (t == 0) { lcnt = 0; ovf = 0; }
  __syncthreads();

  // --- A: centroid ---
  float sx = 0.f, sy = 0.f, sz = 0.f;
  if (t < 256) { sx = kxs[t]; sy = kys[t]; sz = kzs[t]; }
#pragma unroll
  for (int off = 32; off; off >>= 1) {
    sx += __shfl_xor(sx, off, 64);
    sy += __shfl_xor(sy, off, 64);
    sz += __shfl_xor(sz, off, 64);
  }
  if (lane == 0) { wred[wave][0] = sx; wred[wave][1] = sy; wred[wave][2] = sz; }
  __syncthreads();
  if (t == 0) {
    float X = 0.f, Y = 0.f, Z = 0.f;
#pragma unroll
    for (int i = 0; i < 16; i++) { X += wred[i][0]; Y += wred[i][1]; Z += wred[i][2]; }
    bc[0] = X / K; bc[1] = Y / K; bc[2] = Z / K;
  }
  __syncthreads();
  float cx = bc[0], cy = bc[1], cz = bc[2];
  // --- A2: max keypoint distance from centroid ---
  float md = 0.f;
  if (t < 256) {
    float dx = kxs[t] - cx, dy = kys[t] - cy, dz = kzs[t] - cz;
    md = dx * dx + dy * dy + dz * dz;
  }
#pragma unroll
  for (int off = 32; off; off >>= 1) md = fmaxf(md, __shfl_xor(md, off, 64));
  if (lane == 0) wred[wave][0] = md;
  __syncthreads();
  if (t == 0) {
    float m = 0.f;
#pragma unroll
    for (int i = 0; i < 16; i++) m = fmaxf(m, wred[i][0]);
    bc[3] = sqrtf(m);
  }
  __syncthreads();

  // --- B: histogram (in-range bins only) ---
#pragma unroll 1
  for (int i = 0; i < 16; i++) {
    int p = b * NPTS + i * 1024 + t;
    float dx = pos[p * 3 + 0] - cx, dy = pos[p * 3 + 1] - cy, dz = pos[p * 3 + 2] - cz;
    float d2 = dx * dx + dy * dy + dz * dz;
    int bin = (int)(d2 * (1.0f / BINW));
    if (bin < NBINS - 1) atomicAdd(&hist[bin], 1u);
  }
  __syncthreads();

  // --- C: select radius ---
  if (t == 0) {
    unsigned cum = 0; float T2 = -1.f;
    for (int i = 0; i < NBINS - 1; i++) {
      cum += hist[i];
      if (cum >= KNNK) { T2 = (i + 1) * BINW; break; }
    }
    if (T2 < 0.f) bc[4] = 3.0e38f;           // degenerate: keep everything
    else {
      float Rf = sqrtf(T2) + 2.f * bc[3];
      bc[4] = Rf * Rf;
    }
  }
  __syncthreads();
  float r2 = bc[4];

  // --- D: compact candidates into LDS ---
#pragma unroll 1
  for (int i = 0; i < 16; i++) {
    int pl = i * 1024 + t;
    int p = b * NPTS + pl;
    float px = pos[p * 3 + 0], py = pos[p * 3 + 1], pz = pos[p * 3 + 2];
    float dx = px - cx, dy = py - cy, dz = pz - cz;
    float d2 = dx * dx + dy * dy + dz * dz;
    if (d2 <= r2) {
      unsigned u = atomicAdd(&lcnt, 1u);
      if (u < CAP) { cxs[u] = px; cys[u] = py; czs[u] = pz; cis[u] = pl; }
      else ovf = 1;
    }
  }
  __syncthreads();

  // --- E: exact top-16 per keypoint ---
  if (t < 256) {
    float kx = kxs[t], ky = kys[t], kz = kzs[t];
    float dd[KNNK]; int ii[KNNK];
#pragma unroll
    for (int j = 0; j < KNNK; j++) { dd[j] = 1e30f; ii[j] = 0; }
    float mx = 1e30f;
    if (!ovf) {
      int n = (int)lcnt;
      for (int j = 0; j < n; j++) {
        float dx = kx - cxs[j], dy = ky - cys[j], dz = kz - czs[j];
        float d2 = dx * dx + dy * dy + dz * dz;
        if (d2 < mx) {
          int sm = 0; float bv = dd[0];
#pragma unroll
          for (int s = 1; s < KNNK; s++) if (dd[s] > bv) { bv = dd[s]; sm = s; }
#pragma unroll
          for (int s = 0; s < KNNK; s++) if (s == sm) { dd[s] = d2; ii[s] = cis[j]; }
          mx = dd[0];
#pragma unroll
          for (int s = 1; s < KNNK; s++) mx = fmaxf(mx, dd[s]);
        }
      }
    } else {
      // correctness fallback: scan all points (never triggers on sane data)
      for (int j = 0; j < NPTS; j++) {
        const float* pp = pos + (size_t)(b * NPTS + j) * 3;
        float dx = kx - pp[0], dy = ky - pp[1], dz = kz - pp[2];
        float d2 = dx * dx + dy * dy + dz * dz;
        if (d2 < mx) {
          int sm = 0; float bv = dd[0];
#pragma unroll
          for (int s = 1; s < KNNK; s++) if (dd[s] > bv) { bv = dd[s]; sm = s; }
#pragma unroll
          for (int s = 0; s < KNNK; s++) if (s == sm) { dd[s] = d2; ii[s] = j; }
          mx = dd[0];
#pragma unroll
          for (int s = 1; s < KNNK; s++) mx = fmaxf(mx, dd[s]);
        }
      }
    }
    for (int j = 0; j < KNNK; j++) knn[((size_t)(b * K + t)) * KNNK + j] = ii[j];
  }
}

// ---------------------------------------------------------------------------
// Phase 3: gather 16 neighbor feature rows, mean, 32x32 linear.
// ---------------------------------------------------------------------------
__global__ __launch_bounds__(256) void k_extract(
    const float* __restrict__ f, const int* __restrict__ knn,
    const float* __restrict__ We, float* __restrict__ out) {
  __shared__ float P[8][C + 1];
  int tid = threadIdx.x;
  int kp = tid >> 5, c = tid & 31;
  int gk = blockIdx.x * 8 + kp;   // 0..2047
  int b = gk >> 8;
  float s = 0.f;
#pragma unroll
  for (int j = 0; j < KNNK; j++) {
    int pl = knn[(size_t)gk * KNNK + j];
    s += f[((size_t)(b * NPTS + pl)) * C + c];
  }
  P[kp][c] = s * (1.f / KNNK);
  __syncthreads();
  float r = 0.f;
#pragma unroll
  for (int cc = 0; cc < C; cc++) r += P[kp][cc] * We[cc * C + c];
  out[(size_t)gk * C + c] = r;
}

extern "C" void kernel_launch(void* const* d_in, const int* in_sizes, int n_in,
                              void* d_out, int out_size, void* d_ws, size_t ws_size,
                              hipStream_t stream) {
  const float* f   = (const float*)d_in[0];
  const float* pos = (const float*)d_in[1];
  // d_in[2] = W_pool: mathematically unused (bias cancels in segment softmax)
  const float* Wr  = (const float*)d_in[3];
  const float* We  = (const float*)d_in[4];
  float* out = (float*)d_out;

  // nsplit high -> more waves in flight in k_logits (grid was the occupancy
  // limiter at nsplit=128; VGPRs are not: 52 VGPR allows 8 waves/SIMD).
  size_t fixed = 24576 + 131072 + 4096;    // keypoints + knn + pad
  int nsplit;
  if (ws_size >= (size_t)BS * 512 * 256 * 16 + fixed) nsplit = 512;
  else if (ws_size >= (size_t)BS * 128 * 256 * 16 + fixed) nsplit = 128;
  else nsplit = 32;
  size_t partials_bytes = (size_t)BS * nsplit * 256 * 16;

  char* ws = (char*)d_ws;
  float* partials  = (float*)(ws + 0);
  float* keypoints = (float*)(ws + partials_bytes);          // [8][256][3] f32
  int*   knn       = (int*)(ws + partials_bytes + 24576);    // [8][256][16] i32

  k_logits <<<dim3(BS * nsplit), dim3(128),  0, stream>>>(f, pos, Wr, partials, nsplit);
  k_merge  <<<dim3(128),         dim3(256),  0, stream>>>(partials, keypoints, nsplit);
  k_graph  <<<dim3(BS),          dim3(1024), 0, stream>>>(pos, keypoints, knn);
  k_extract<<<dim3((BS * K) / 8), dim3(256), 0, stream>>>(f, knn, We, out);
}